// Round 16
// baseline (349.864 us; speedup 1.0000x reference)
//
#include <hip/hip_runtime.h>
#include <hip/hip_bf16.h>

// ARMA GNN (K=3 stacks, T=2 layers, F_in=64, DIM=32) on MI355X.
// Round 16: non-temporal loads for streamed csr/root in the gather props
// (protect L2 residency of the gather table); scan2+scan3 merged; dummy-row
// zeroing folded into fill_csr_bucket. Core prop/mm structure = r14/r15.

#define KSTACK 3
#define DIM    32
#define FDIM   96    // KSTACK*DIM
#define NB     256   // dst buckets (dst>>9; N<=131072)
#define TILE   4096  // edges per grouping block

typedef __hip_bfloat16 bf16;
typedef _Float16 f16;
typedef _Float16 halfx2 __attribute__((ext_vector_type(2)));
typedef unsigned int uintx2 __attribute__((ext_vector_type(2)));
typedef unsigned int uintx4 __attribute__((ext_vector_type(4)));

__device__ __forceinline__ float dot2h(unsigned int a, unsigned int b, float c) {
#if __has_builtin(__builtin_amdgcn_fdot2)
    return __builtin_amdgcn_fdot2(__builtin_bit_cast(halfx2, a),
                                  __builtin_bit_cast(halfx2, b), c, false);
#else
    halfx2 ha = __builtin_bit_cast(halfx2, a);
    halfx2 hb = __builtin_bit_cast(halfx2, b);
    return c + (float)ha.x * (float)hb.x + (float)ha.y * (float)hb.y;
#endif
}

__device__ __forceinline__ unsigned int pkh(float lo, float hi) {
    return __builtin_bit_cast(unsigned int, __builtin_amdgcn_cvt_pkrtz(lo, hi));
}

__device__ __forceinline__ halfx2 h2(unsigned int q) {
    return __builtin_bit_cast(halfx2, q);
}

// non-temporal 16B offset load (streamed once -> don't pollute L2)
__device__ __forceinline__ uintx4 ntl4(const int* __restrict__ p) {
    return __builtin_nontemporal_load(reinterpret_cast<const uintx4*>(p));
}
__device__ __forceinline__ uintx2 ntl2(const void* __restrict__ p) {
    return __builtin_nontemporal_load(reinterpret_cast<const uintx2*>(p));
}

// ---------------- graph build (no random global atomics) ----------------

__global__ void zero_int_kernel(int* __restrict__ p, int n) {
    int i = blockIdx.x * 256 + threadIdx.x;
    if (i < n) p[i] = 0;
}

// per-block LDS histogram of dst>>9 -> global bcnt (256 low-contention atomics/block)
__global__ __launch_bounds__(256) void bucket_hist_kernel(const int* __restrict__ dst,
                                                          int* __restrict__ bcnt, int E) {
    __shared__ int cnt[NB];
    for (int i = threadIdx.x; i < NB; i += 256) cnt[i] = 0;
    __syncthreads();
    const int e0 = blockIdx.x * TILE;
    const int count = min(TILE, E - e0);
    for (int u = threadIdx.x; u < count; u += 256)
        atomicAdd(&cnt[dst[e0 + u] >> 9], 1);
    __syncthreads();
    for (int i = threadIdx.x; i < NB; i += 256)
        if (cnt[i]) atomicAdd(&bcnt[i], cnt[i]);
}

__global__ __launch_bounds__(256) void bucket_scan_kernel(const int* __restrict__ bcnt,
                                                          int* __restrict__ gcur,
                                                          int* __restrict__ gbase) {
    __shared__ int s[NB];
    const int t = threadIdx.x;
    int v = bcnt[t];
    s[t] = v;
    __syncthreads();
    for (int off = 1; off < NB; off <<= 1) {
        int add = (t >= off) ? s[t - off] : 0;
        __syncthreads();
        s[t] += add;
        __syncthreads();
    }
    gcur[t]  = s[t] - v;   // mutable cursor for chunk reservation
    gbase[t] = s[t] - v;   // stable bucket base
}

// counting-sort pass: group edges by dst>>9; packed u32 output ((dst&511)<<23|src)
__global__ __launch_bounds__(256) void group_edges_kernel(
    const int* __restrict__ src, const int* __restrict__ dst,
    int* __restrict__ gcur, unsigned int* __restrict__ grouped, int E)
{
    __shared__ int cnt[NB], pref[NB], lbase[NB], lofs[NB], gres[NB];
    __shared__ int2 stage[TILE];
    const int tid = threadIdx.x;
    const int e0 = blockIdx.x * TILE;
    const int count = min(TILE, E - e0);
    cnt[tid] = 0;
    __syncthreads();
    #pragma unroll
    for (int u = 0; u < TILE / 256; ++u) {
        int idx = u * 256 + tid;
        if (idx < count) atomicAdd(&cnt[dst[e0 + idx] >> 9], 1);
    }
    __syncthreads();
    int v = cnt[tid];
    pref[tid] = v;
    __syncthreads();
    for (int off = 1; off < NB; off <<= 1) {
        int add = (tid >= off) ? pref[tid - off] : 0;
        __syncthreads();
        pref[tid] += add;
        __syncthreads();
    }
    int ex = pref[tid] - v;
    lbase[tid] = ex;
    lofs[tid]  = ex;
    gres[tid] = atomicAdd(&gcur[tid], v);   // reserve global chunk for this block
    __syncthreads();
    #pragma unroll
    for (int u = 0; u < TILE / 256; ++u) {
        int idx = u * 256 + tid;
        if (idx < count) {
            int e = e0 + idx;
            int d = dst[e];
            int lp = atomicAdd(&lofs[d >> 9], 1);
            stage[lp] = make_int2(src[e], d);
        }
    }
    __syncthreads();
    for (int i = tid; i < count; i += 256) {
        int2 pr = stage[i];
        int b = pr.y >> 9;
        grouped[gres[b] + (i - lbase[b])] =
            ((unsigned int)(pr.y & 511) << 23) | (unsigned int)pr.x;  // coalesced
    }
}

// fused per-bucket: degree histogram from grouped + dinv + deg4 scan -> off4
__global__ __launch_bounds__(512) void scan1_kernel(
    const unsigned int* __restrict__ grouped, const int* __restrict__ gbase,
    const int* __restrict__ bcnt, float* __restrict__ dinv,
    int* __restrict__ off4, int* __restrict__ bsums, int N)
{
    __shared__ int h[512];
    __shared__ int tmp[512];
    const int b  = blockIdx.x;
    const int t  = threadIdx.x;
    const int nb = b * 512;
    h[t] = 0;
    __syncthreads();
    const int e0 = gbase[b], cnt = bcnt[b];
    for (int u = t; u < cnt; u += 512)
        atomicAdd(&h[grouped[e0 + u] >> 23], 1);
    __syncthreads();
    const int i  = nb + t;
    const int dg = h[t];
    if (i < N) dinv[i] = (dg > 0) ? rsqrtf((float)dg) : 0.0f;
    int v = (i < N) ? ((dg + 3) & ~3) : 0;
    tmp[t] = v;
    __syncthreads();
    for (int off = 1; off < 512; off <<= 1) {
        int add = (t >= off) ? tmp[t - off] : 0;
        __syncthreads();
        tmp[t] += add;
        __syncthreads();
    }
    if (i <= N) off4[i] = tmp[t] - v;            // block-local exclusive
    if (t == 511) bsums[b] = tmp[511];           // block total
}

// merged scan2+scan3: each block scans all (<=256) block sums in LDS, applies
__global__ __launch_bounds__(256) void scan23_kernel(int* __restrict__ off4,
                                                     const int* __restrict__ bsums,
                                                     int nsb, int N) {
    __shared__ int s[256], ex[256];
    const int t = threadIdx.x;
    int v = (t < nsb) ? bsums[t] : 0;
    s[t] = v;
    __syncthreads();
    for (int off = 1; off < 256; off <<= 1) {
        int add = (t >= off) ? s[t - off] : 0;
        __syncthreads();
        s[t] += add;
        __syncthreads();
    }
    ex[t] = s[t] - v;   // exclusive prefix
    __syncthreads();
    int i = blockIdx.x * 256 + t;
    if (i <= N) off4[i] += ex[i >> 9];
}

// per-bucket CSR fill: LDS cursors seeded from off4; fills edges + pad slots.
// Block 0 additionally zeroes the dummy rows of the three gather tables.
__global__ __launch_bounds__(256) void fill_csr_bucket_kernel(
    const unsigned int* __restrict__ grouped, const int* __restrict__ gbase,
    const int* __restrict__ bcnt, const int* __restrict__ off4,
    int* __restrict__ csr, f16* __restrict__ ga, f16* __restrict__ gb,
    f16* __restrict__ gc, int N, int dummy)
{
    __shared__ int lofs[512];
    const int b  = blockIdx.x;
    const int nb = b * 512;
    for (int i = threadIdx.x; i < 512; i += 256)
        lofs[i] = (nb + i < N) ? off4[nb + i] : 0;
    __syncthreads();
    const int e0 = gbase[b], cnt = bcnt[b];
    for (int u = threadIdx.x; u < cnt; u += 256) {
        unsigned int pe = grouped[e0 + u];
        int pos = atomicAdd(&lofs[pe >> 23], 1);
        csr[pos] = (int)(pe & 0x7fffffu) << 6;   // src*64
    }
    __syncthreads();
    for (int i = threadIdx.x; i < 512; i += 256) {
        int n = nb + i;
        if (n < N) {
            int p = lofs[i];            // = off4[n] + deg[n]
            int e = off4[n + 1];
            for (; p < e; ++p) csr[p] = dummy;
        }
    }
    if (b == 0) {
        int t = threadIdx.x;
        if (t < FDIM) {
            ga[(long)N * FDIM + t] = (f16)0.f;
            gb[(long)N * FDIM + t] = (f16)0.f;
        }
        if (t < DIM) gc[(long)N * DIM + t] = (f16)0.f;
    }
}

// ---------------- init GEMM (packed-f16 dot2) ----------------
// 64 nodes/block; thread (g,o): nodes 8g..8g+7, output col o, all 3 stacks.
// x staged as packed f16 pairs [F2][64]; weights as packed-pair tables.
// outA (gather table) and rootb (bias folded) written f16.

template <int FIN, bool MEANROOT, bool XF16>
__global__ __launch_bounds__(256) void mm_init_kernel(
    const float* __restrict__ xf,   // [N, FIN] fp32 (if !XF16)
    const f16*   __restrict__ xh,   // [N, FIN] f16  (if XF16)
    const float* __restrict__ wA,   // [K, FIN, 32]
    const float* __restrict__ wB,   // [K, FIN, 32]
    const float* __restrict__ dinv, // [N]
    f16*   __restrict__ outA,       // [N+1, 96] f16 (row N maintained elsewhere)
    f16*   __restrict__ rootb,      // [N, 96] f16, = x@wB + bias
    float* __restrict__ rootm,      // [N, 32] = mean_k(x@wB + bias)   (if MEANROOT)
    const float* __restrict__ bias, // [96]
    int N)
{
    constexpr int F2 = FIN / 2;
    __shared__ unsigned int swA2[KSTACK * F2 * 32];
    __shared__ unsigned int swB2[KSTACK * F2 * 32];
    __shared__ unsigned int sx2[F2 * 64];
    const int tid = threadIdx.x;
    const int n0  = blockIdx.x * 64;

    for (int i = tid; i < KSTACK * F2 * 32; i += 256) {
        int k = i / (F2 * 32), r = i % (F2 * 32), f2 = r >> 5, o = r & 31;
        swA2[i] = pkh(wA[(k * FIN + 2 * f2) * 32 + o], wA[(k * FIN + 2 * f2 + 1) * 32 + o]);
        swB2[i] = pkh(wB[(k * FIN + 2 * f2) * 32 + o], wB[(k * FIN + 2 * f2 + 1) * 32 + o]);
    }
    for (int i = tid; i < 64 * F2; i += 256) {
        int jj = i / F2, f2 = i % F2;
        int n = n0 + jj; if (n >= N) n = N - 1;
        unsigned int v;
        if (XF16) v = *reinterpret_cast<const unsigned int*>(xh + (long)n * FIN + 2 * f2);
        else      v = pkh(xf[(long)n * FIN + 2 * f2], xf[(long)n * FIN + 2 * f2 + 1]);
        sx2[f2 * 64 + jj] = v;
    }
    __syncthreads();

    const int o = tid & 31;
    const int g = tid >> 5;
    float bz[KSTACK];
    #pragma unroll
    for (int k = 0; k < KSTACK; ++k) bz[k] = bias[k * 32 + o];
    float accA[8][KSTACK];
    float accB[8][KSTACK];
    #pragma unroll
    for (int jj = 0; jj < 8; ++jj)
        #pragma unroll
        for (int k = 0; k < KSTACK; ++k) { accA[jj][k] = 0.f; accB[jj][k] = 0.f; }

    #pragma unroll 2
    for (int f2 = 0; f2 < F2; ++f2) {
        uint4 xlo = *reinterpret_cast<const uint4*>(&sx2[f2 * 64 + 8 * g]);
        uint4 xhi = *reinterpret_cast<const uint4*>(&sx2[f2 * 64 + 8 * g + 4]);
        unsigned int xp[8] = {xlo.x, xlo.y, xlo.z, xlo.w, xhi.x, xhi.y, xhi.z, xhi.w};
        #pragma unroll
        for (int k = 0; k < KSTACK; ++k) {
            unsigned int wa2 = swA2[(k * F2 + f2) * 32 + o];
            unsigned int wb2 = swB2[(k * F2 + f2) * 32 + o];
            #pragma unroll
            for (int jj = 0; jj < 8; ++jj) {
                accA[jj][k] = dot2h(xp[jj], wa2, accA[jj][k]);
                accB[jj][k] = dot2h(xp[jj], wb2, accB[jj][k]);
            }
        }
    }

    #pragma unroll
    for (int jj = 0; jj < 8; ++jj) {
        long n = n0 + 8 * g + jj;
        if (n < N) {
            const float di = dinv[n];
            float rsum = 0.f;
            #pragma unroll
            for (int k = 0; k < KSTACK; ++k) {
                float rb = accB[jj][k] + bz[k];
                outA[n * FDIM + k * 32 + o]  = (f16)(accA[jj][k] * di);
                rootb[n * FDIM + k * 32 + o] = (f16)rb;
                rsum += rb;
            }
            if (MEANROOT)
                rootm[n * 32 + o] = rsum * (1.0f / 3.0f);
        }
    }
}

// ---------------- gather helpers ----------------

// dual-dst gather over 192B f16 rows, unroll 8 (16 row-loads + 4 offset-loads
// in flight per 32-lane group). csr stores src*64; 192B-row offset = 3*o.
// csr offset loads are NON-TEMPORAL (streamed once); row loads stay cached.
#define GATHER_LOOP8()                                                         \
    const int m = max(nA, nB);                                                 \
    halfx2 aA01a = {0, 0}, aA23a = {0, 0}, aA01b = {0, 0}, aA23b = {0, 0};     \
    halfx2 aB01a = {0, 0}, aB23a = {0, 0}, aB01b = {0, 0}, aB23b = {0, 0};     \
    for (int b = 0; b < m; b += 8) {                                           \
        uintx4 tA0 = ntl4(csr + iA + b);                                       \
        uintx4 tA1 = ntl4(csr + iA + b + 4);                                   \
        uintx4 tB0 = ntl4(csr + iB + b);                                       \
        uintx4 tB1 = ntl4(csr + iB + b + 4);                                   \
        const int rA = nA - b, rB = nB - b;                                    \
        int oA0 = rA > 0 ? (int)tA0.x : dummy;                                 \
        int oA1 = rA > 1 ? (int)tA0.y : dummy;                                 \
        int oA2 = rA > 2 ? (int)tA0.z : dummy;                                 \
        int oA3 = rA > 3 ? (int)tA0.w : dummy;                                 \
        int oA4 = rA > 4 ? (int)tA1.x : dummy;                                 \
        int oA5 = rA > 5 ? (int)tA1.y : dummy;                                 \
        int oA6 = rA > 6 ? (int)tA1.z : dummy;                                 \
        int oA7 = rA > 7 ? (int)tA1.w : dummy;                                 \
        int oB0 = rB > 0 ? (int)tB0.x : dummy;                                 \
        int oB1 = rB > 1 ? (int)tB0.y : dummy;                                 \
        int oB2 = rB > 2 ? (int)tB0.z : dummy;                                 \
        int oB3 = rB > 3 ? (int)tB0.w : dummy;                                 \
        int oB4 = rB > 4 ? (int)tB1.x : dummy;                                 \
        int oB5 = rB > 5 ? (int)tB1.y : dummy;                                 \
        int oB6 = rB > 6 ? (int)tB1.z : dummy;                                 \
        int oB7 = rB > 7 ? (int)tB1.w : dummy;                                 \
        if (ld) {                                                              \
            uint2 qA0 = *reinterpret_cast<const uint2*>(base + 3 * oA0 + lb);  \
            uint2 qA1 = *reinterpret_cast<const uint2*>(base + 3 * oA1 + lb);  \
            uint2 qA2 = *reinterpret_cast<const uint2*>(base + 3 * oA2 + lb);  \
            uint2 qA3 = *reinterpret_cast<const uint2*>(base + 3 * oA3 + lb);  \
            uint2 qA4 = *reinterpret_cast<const uint2*>(base + 3 * oA4 + lb);  \
            uint2 qA5 = *reinterpret_cast<const uint2*>(base + 3 * oA5 + lb);  \
            uint2 qA6 = *reinterpret_cast<const uint2*>(base + 3 * oA6 + lb);  \
            uint2 qA7 = *reinterpret_cast<const uint2*>(base + 3 * oA7 + lb);  \
            uint2 qB0 = *reinterpret_cast<const uint2*>(base + 3 * oB0 + lb);  \
            uint2 qB1 = *reinterpret_cast<const uint2*>(base + 3 * oB1 + lb);  \
            uint2 qB2 = *reinterpret_cast<const uint2*>(base + 3 * oB2 + lb);  \
            uint2 qB3 = *reinterpret_cast<const uint2*>(base + 3 * oB3 + lb);  \
            uint2 qB4 = *reinterpret_cast<const uint2*>(base + 3 * oB4 + lb);  \
            uint2 qB5 = *reinterpret_cast<const uint2*>(base + 3 * oB5 + lb);  \
            uint2 qB6 = *reinterpret_cast<const uint2*>(base + 3 * oB6 + lb);  \
            uint2 qB7 = *reinterpret_cast<const uint2*>(base + 3 * oB7 + lb);  \
            aA01a += h2(qA0.x); aA23a += h2(qA0.y);                            \
            aA01b += h2(qA1.x); aA23b += h2(qA1.y);                            \
            aA01a += h2(qA2.x); aA23a += h2(qA2.y);                            \
            aA01b += h2(qA3.x); aA23b += h2(qA3.y);                            \
            aA01a += h2(qA4.x); aA23a += h2(qA4.y);                            \
            aA01b += h2(qA5.x); aA23b += h2(qA5.y);                            \
            aA01a += h2(qA6.x); aA23a += h2(qA6.y);                            \
            aA01b += h2(qA7.x); aA23b += h2(qA7.y);                            \
            aB01a += h2(qB0.x); aB23a += h2(qB0.y);                            \
            aB01b += h2(qB1.x); aB23b += h2(qB1.y);                            \
            aB01a += h2(qB2.x); aB23a += h2(qB2.y);                            \
            aB01b += h2(qB3.x); aB23b += h2(qB3.y);                            \
            aB01a += h2(qB4.x); aB23a += h2(qB4.y);                            \
            aB01b += h2(qB5.x); aB23b += h2(qB5.y);                            \
            aB01a += h2(qB6.x); aB23a += h2(qB6.y);                            \
            aB01b += h2(qB7.x); aB23b += h2(qB7.y);                            \
        }                                                                      \
    }                                                                          \
    const float aA0 = (float)aA01a.x + (float)aA01b.x;                         \
    const float aA1 = (float)aA01a.y + (float)aA01b.y;                         \
    const float aA2 = (float)aA23a.x + (float)aA23b.x;                         \
    const float aA3 = (float)aA23a.y + (float)aA23b.y;                         \
    const float aB0 = (float)aB01a.x + (float)aB01b.x;                         \
    const float aB1 = (float)aB01a.y + (float)aB01b.y;                         \
    const float aB2 = (float)aB23a.x + (float)aB23b.x;                         \
    const float aB3 = (float)aB23a.y + (float)aB23b.y;

// setup shared by all dual-dst gather kernels (f16 root, bias folded).
// root rows are streamed once -> non-temporal.
#define DST_SETUP()                                                            \
    const int dA = blockIdx.x * 16 + j;                                        \
    const int dB = dA + 8;                                                     \
    const bool vA = dA < N, vB = dB < N;                                       \
    const int dummy = N * 64;                                                  \
    const bool ld  = lane < 24;                                                \
    const int  lb  = lane * 8;                                                 \
    const char* base = (const char*)in;                                        \
    halfx2 rA01 = {0, 0}, rA23 = {0, 0}, rB01 = {0, 0}, rB23 = {0, 0};         \
    int iA = 0, nA = 0, iB = 0, nB = 0;                                        \
    float diA = 0.f, diB = 0.f;                                                \
    if (vA) {                                                                  \
        iA = off4[dA]; nA = off4[dA + 1] - iA; diA = dinv[dA];                 \
        if (ld) {                                                              \
            uintx2 rr = ntl2((const char*)root + (long)dA * 192 + lb);         \
            rA01 = h2(rr.x); rA23 = h2(rr.y);                                  \
        }                                                                      \
    }                                                                          \
    if (vB) {                                                                  \
        iB = off4[dB]; nB = off4[dB + 1] - iB; diB = dinv[dB];                 \
        if (ld) {                                                              \
            uintx2 rr = ntl2((const char*)root + (long)dB * 192 + lb);         \
            rB01 = h2(rr.x); rB23 = h2(rr.y);                                  \
        }                                                                      \
    }

// packed-f16 96-wide GEMV: r_k = sum_f v[k*32+f] * w[k][f][lane]
__device__ __forceinline__ void gemv96(const unsigned int* __restrict__ sv,
                                       const unsigned int* __restrict__ sw2,
                                       int lane, float& r0, float& r1, float& r2) {
    float o[KSTACK];
    #pragma unroll
    for (int k = 0; k < KSTACK; ++k) {
        const unsigned int* sp = sv + k * 16;
        uint4 s0 = *reinterpret_cast<const uint4*>(sp);
        uint4 s1 = *reinterpret_cast<const uint4*>(sp + 4);
        uint4 s2 = *reinterpret_cast<const uint4*>(sp + 8);
        uint4 s3 = *reinterpret_cast<const uint4*>(sp + 12);
        const unsigned int* wp = sw2 + k * 512 + lane;
        float a = 0.f;
        a = dot2h(s0.x, wp[0],   a); a = dot2h(s0.y, wp[32],  a);
        a = dot2h(s0.z, wp[64],  a); a = dot2h(s0.w, wp[96],  a);
        a = dot2h(s1.x, wp[128], a); a = dot2h(s1.y, wp[160], a);
        a = dot2h(s1.z, wp[192], a); a = dot2h(s1.w, wp[224], a);
        a = dot2h(s2.x, wp[256], a); a = dot2h(s2.y, wp[288], a);
        a = dot2h(s2.z, wp[320], a); a = dot2h(s2.w, wp[352], a);
        a = dot2h(s3.x, wp[384], a); a = dot2h(s3.y, wp[416], a);
        a = dot2h(s3.z, wp[448], a); a = dot2h(s3.w, wp[480], a);
        o[k] = a;
    }
    r0 = o[0]; r1 = o[1]; r2 = o[2];
}

// ---------------- prop #1 (layer 1): gather + relu + fused 32x32 GEMV ------
__global__ __launch_bounds__(256) void prop_mm_kernel(
    const f16*   __restrict__ in,       // [N+1, 96] pre-scaled by dinv[src]
    const int*   __restrict__ off4,     // [N+1]
    const int*   __restrict__ csr,      // src*64, 4-aligned segments
    const float* __restrict__ dinv,
    const f16*   __restrict__ root,     // [N, 96] f16, bias folded
    const float* __restrict__ w,        // [K,32,32]
    f16* __restrict__ out, int N)       // [N+1, 96]; row N maintained elsewhere
{
    __shared__ unsigned int sw2[KSTACK * 512];   // lane-major packed-f16 weight pairs
    __shared__ unsigned int sv2[16][48];         // packed-f16 activated vectors
    const int tid = threadIdx.x;
    for (int i = tid; i < KSTACK * 512; i += 256) {
        int k = i >> 9, r = i & 511, t = r >> 5, o = r & 31;
        sw2[i] = pkh(w[(k * 32 + 2 * t) * 32 + o], w[(k * 32 + 2 * t + 1) * 32 + o]);
    }
    __syncthreads();
    const int lane = tid & 31;
    const int j    = tid >> 5;
    DST_SETUP();

    GATHER_LOOP8();

    if (ld) {
        if (vA) {
            float v0 = fmaxf(aA0 * diA + (float)rA01.x, 0.f);
            float v1 = fmaxf(aA1 * diA + (float)rA01.y, 0.f);
            float v2 = fmaxf(aA2 * diA + (float)rA23.x, 0.f);
            float v3 = fmaxf(aA3 * diA + (float)rA23.y, 0.f);
            sv2[j][2 * lane]     = pkh(v0, v1);
            sv2[j][2 * lane + 1] = pkh(v2, v3);
        }
        if (vB) {
            float v0 = fmaxf(aB0 * diB + (float)rB01.x, 0.f);
            float v1 = fmaxf(aB1 * diB + (float)rB01.y, 0.f);
            float v2 = fmaxf(aB2 * diB + (float)rB23.x, 0.f);
            float v3 = fmaxf(aB3 * diB + (float)rB23.y, 0.f);
            sv2[j + 8][2 * lane]     = pkh(v0, v1);
            sv2[j + 8][2 * lane + 1] = pkh(v2, v3);
        }
    }
    // same-wave LDS write->read: no barrier needed
    if (vA) {
        float o0, o1, o2;
        gemv96(&sv2[j][0], sw2, lane, o0, o1, o2);
        out[(long)dA * FDIM + lane]      = (f16)(o0 * diA);
        out[(long)dA * FDIM + 32 + lane] = (f16)(o1 * diA);
        out[(long)dA * FDIM + 64 + lane] = (f16)(o2 * diA);
    }
    if (vB) {
        float o0, o1, o2;
        gemv96(&sv2[j + 8][0], sw2, lane, o0, o1, o2);
        out[(long)dB * FDIM + lane]      = (f16)(o0 * diB);
        out[(long)dB * FDIM + 32 + lane] = (f16)(o1 * diB);
        out[(long)dB * FDIM + 64 + lane] = (f16)(o2 * diB);
    }
}

// -------- prop #2 (layer 1): gather + relu + mean over stacks + relu -------
__global__ __launch_bounds__(256) void prop_mean_kernel(
    const f16*   __restrict__ in,       // [N+1, 96] pre-scaled by dinv[src]
    const int*   __restrict__ off4,
    const int*   __restrict__ csr,
    const float* __restrict__ dinv,
    const f16*   __restrict__ root,     // [N, 96] f16, bias folded
    f16* __restrict__ out,              // [N, 32] f16
    int N)
{
    __shared__ float sv[16][FDIM];
    const int tid = threadIdx.x;
    const int lane = tid & 31;
    const int j    = tid >> 5;
    DST_SETUP();

    GATHER_LOOP8();

    if (ld) {
        if (vA) {
            sv[j][4*lane]   = fmaxf(aA0 * diA + (float)rA01.x, 0.f);
            sv[j][4*lane+1] = fmaxf(aA1 * diA + (float)rA01.y, 0.f);
            sv[j][4*lane+2] = fmaxf(aA2 * diA + (float)rA23.x, 0.f);
            sv[j][4*lane+3] = fmaxf(aA3 * diA + (float)rA23.y, 0.f);
        }
        if (vB) {
            sv[j+8][4*lane]   = fmaxf(aB0 * diB + (float)rB01.x, 0.f);
            sv[j+8][4*lane+1] = fmaxf(aB1 * diB + (float)rB01.y, 0.f);
            sv[j+8][4*lane+2] = fmaxf(aB2 * diB + (float)rB23.x, 0.f);
            sv[j+8][4*lane+3] = fmaxf(aB3 * diB + (float)rB23.y, 0.f);
        }
    }
    if (vA) {
        float mv = fmaxf((sv[j][lane] + sv[j][32 + lane] + sv[j][64 + lane]) * (1.0f / 3.0f), 0.f);
        out[(long)dA * 32 + lane] = (f16)mv;
    }
    if (vB) {
        float mv = fmaxf((sv[j+8][lane] + sv[j+8][32 + lane] + sv[j+8][64 + lane]) * (1.0f / 3.0f), 0.f);
        out[(long)dB * 32 + lane] = (f16)mv;
    }
}

// ---- prop #3 (layer 2): gather + identity + GEMV, write k-MEAN (32-wide) ---
__global__ __launch_bounds__(256) void prop_mm_mean_kernel(
    const f16*   __restrict__ in,       // [N+1, 96] pre-scaled by dinv[src]
    const int*   __restrict__ off4,
    const int*   __restrict__ csr,
    const float* __restrict__ dinv,
    const f16*   __restrict__ root,     // [N, 96] f16, bias folded
    const float* __restrict__ w,        // [K,32,32]
    f16* __restrict__ out, int N)       // [N+1, 32]; row N maintained elsewhere
{
    __shared__ unsigned int sw2[KSTACK * 512];
    __shared__ unsigned int sv2[16][48];
    const int tid = threadIdx.x;
    for (int i = tid; i < KSTACK * 512; i += 256) {
        int k = i >> 9, r = i & 511, t = r >> 5, o = r & 31;
        sw2[i] = pkh(w[(k * 32 + 2 * t) * 32 + o], w[(k * 32 + 2 * t + 1) * 32 + o]);
    }
    __syncthreads();
    const int lane = tid & 31;
    const int j    = tid >> 5;
    DST_SETUP();

    GATHER_LOOP8();

    if (ld) {
        if (vA) {
            sv2[j][2 * lane]     = pkh(aA0 * diA + (float)rA01.x, aA1 * diA + (float)rA01.y);
            sv2[j][2 * lane + 1] = pkh(aA2 * diA + (float)rA23.x, aA3 * diA + (float)rA23.y);
        }
        if (vB) {
            sv2[j + 8][2 * lane]     = pkh(aB0 * diB + (float)rB01.x, aB1 * diB + (float)rB01.y);
            sv2[j + 8][2 * lane + 1] = pkh(aB2 * diB + (float)rB23.x, aB3 * diB + (float)rB23.y);
        }
    }
    // same-wave LDS write->read: no barrier needed
    if (vA) {
        float o0, o1, o2;
        gemv96(&sv2[j][0], sw2, lane, o0, o1, o2);
        out[(long)dA * 32 + lane] = (f16)((o0 + o1 + o2) * (diA * (1.0f / 3.0f)));
    }
    if (vB) {
        float o0, o1, o2;
        gemv96(&sv2[j + 8][0], sw2, lane, o0, o1, o2);
        out[(long)dB * 32 + lane] = (f16)((o0 + o1 + o2) * (diB * (1.0f / 3.0f)));
    }
}

// ---- prop #4 (layer 2, final): 64B-row gather + rootm add (fp32 out) ------
__global__ __launch_bounds__(256) void prop_mean2_kernel(
    const f16*   __restrict__ in,       // [N+1, 32] k-mean rows, dinv-prescaled
    const int*   __restrict__ off4,
    const int*   __restrict__ csr,      // src*64
    const float* __restrict__ dinv,
    const float* __restrict__ rootm,    // [N, 32] mean_k(root) incl. bias
    float* __restrict__ out,            // [N, 32]
    int N)
{
    const int lane = threadIdx.x & 15;
    const int g    = threadIdx.x >> 4;      // 16 groups/block
    const int d    = blockIdx.x * 16 + g;
    if (d >= N) return;
    const int dummy = N * 64;
    const int lb = lane * 4;                 // 4B (2 features) per lane
    const char* base = (const char*)in;
    const int i0 = off4[d];
    const int n  = off4[d + 1] - i0;
    halfx2 aa = {0, 0}, ab = {0, 0};
    for (int b = 0; b < n; b += 8) {
        uintx4 t0 = ntl4(csr + i0 + b);
        uintx4 t1 = ntl4(csr + i0 + b + 4);
        const int r = n - b;
        int o0 = r > 0 ? (int)t0.x : dummy;
        int o1 = r > 1 ? (int)t0.y : dummy;
        int o2 = r > 2 ? (int)t0.z : dummy;
        int o3 = r > 3 ? (int)t0.w : dummy;
        int o4 = r > 4 ? (int)t1.x : dummy;
        int o5 = r > 5 ? (int)t1.y : dummy;
        int o6 = r > 6 ? (int)t1.z : dummy;
        int o7 = r > 7 ? (int)t1.w : dummy;
        unsigned int q0 = *reinterpret_cast<const unsigned int*>(base + o0 + lb);
        unsigned int q1 = *reinterpret_cast<const unsigned int*>(base + o1 + lb);
        unsigned int q2 = *reinterpret_cast<const unsigned int*>(base + o2 + lb);
        unsigned int q3 = *reinterpret_cast<const unsigned int*>(base + o3 + lb);
        unsigned int q4 = *reinterpret_cast<const unsigned int*>(base + o4 + lb);
        unsigned int q5 = *reinterpret_cast<const unsigned int*>(base + o5 + lb);
        unsigned int q6 = *reinterpret_cast<const unsigned int*>(base + o6 + lb);
        unsigned int q7 = *reinterpret_cast<const unsigned int*>(base + o7 + lb);
        aa += h2(q0); ab += h2(q1); aa += h2(q2); ab += h2(q3);
        aa += h2(q4); ab += h2(q5); aa += h2(q6); ab += h2(q7);
    }
    const float di = dinv[d];
    float a0 = (float)aa.x + (float)ab.x;
    float a1 = (float)aa.y + (float)ab.y;
    float2 rm = *reinterpret_cast<const float2*>(rootm + (long)d * 32 + 2 * lane);
    float2 res = make_float2(a0 * di + rm.x, a1 * di + rm.y);
    *reinterpret_cast<float2*>(out + (long)d * 32 + 2 * lane) = res;
}

// ---------------- launch ----------------

extern "C" void kernel_launch(void* const* d_in, const int* in_sizes, int n_in,
                              void* d_out, int out_size, void* d_ws, size_t ws_size,
                              hipStream_t stream) {
    const float* x       = (const float*)d_in[0];
    const int*   edge    = (const int*)  d_in[1];
    const float* w1_init = (const float*)d_in[2];
    const float* w1      = (const float*)d_in[3];
    const float* w1_root = (const float*)d_in[4];
    const float* b1      = (const float*)d_in[5];
    const float* w2_init = (const float*)d_in[6];
    const float* w2      = (const float*)d_in[7];
    const float* w2_root = (const float*)d_in[8];
    const float* b2      = (const float*)d_in[9];
    float* out = (float*)d_out;

    const int N = in_sizes[0] / 64;
    const int E = in_sizes[1] / 2;
    const int* src = edge;
    const int* dst = edge + E;
    const int E4max = E + 3 * N;   // upper bound on padded CSR length

    // workspace carve (256B aligned)
    char* p = (char*)d_ws;
    auto alloc = [&](size_t bytes) { void* r = (void*)p; p += (bytes + 255) & ~(size_t)255; return r; };
    float* dinv     = (float*)alloc((size_t)N * 4);
    int*   off4     = (int*)  alloc((size_t)(N + 1) * 4);
    const int nScanBlocks = (N + 1 + 511) / 512;   // == per-bucket scan1 grid
    int*   bsums    = (int*)  alloc((size_t)nScanBlocks * 4);
    int*   bcnt     = (int*)  alloc((size_t)NB * 4);
    int*   gcur     = (int*)  alloc((size_t)NB * 4);
    int*   gbase    = (int*)  alloc((size_t)NB * 4);
    int*   csr_boff = (int*)  alloc((size_t)(E4max + 1024) * 4);
    f16*   gatherA  = (f16*)  alloc((size_t)(N + 1) * FDIM * 2);
    f16*   gatherB  = (f16*)  alloc((size_t)(N + 1) * FDIM * 2);
    f16*   grow2    = (f16*)  alloc((size_t)(N + 1) * DIM * 2);
    f16*   rootb    = (f16*)  alloc((size_t)N * FDIM * 2);
    float* rootm    = (float*)alloc((size_t)N * DIM * 4);
    f16*   hbuf     = (f16*)  alloc((size_t)N * DIM * 2);
    unsigned int* grouped = (unsigned int*)alloc((size_t)E * 4);
    (void)ws_size; (void)n_in; (void)out_size;

    const int gN1    = (N + 1 + 255) / 256;
    const int gT     = (E + TILE - 1) / TILE;
    const int gNod64 = (N + 63) / 64;     // 64 rows per block (mm_init)
    const int gNod16 = (N + 15) / 16;     // 16 dst per block (props)

    // ---- graph structure (rebuilt every call; deterministic topology) ----
    zero_int_kernel<<<1, 256, 0, stream>>>(bcnt, NB);
    bucket_hist_kernel<<<gT, 256, 0, stream>>>(dst, bcnt, E);
    bucket_scan_kernel<<<1, NB, 0, stream>>>(bcnt, gcur, gbase);
    group_edges_kernel<<<gT, 256, 0, stream>>>(src, dst, gcur, grouped, E);
    scan1_kernel<<<nScanBlocks, 512, 0, stream>>>(grouped, gbase, bcnt, dinv, off4, bsums, N);
    scan23_kernel<<<gN1, 256, 0, stream>>>(off4, bsums, nScanBlocks, N);
    fill_csr_bucket_kernel<<<nScanBlocks, 256, 0, stream>>>(grouped, gbase, bcnt, off4,
                                                            csr_boff, gatherA, gatherB, grow2,
                                                            N, N * 64);

    // ---- layer 1 (act = relu) ----
    mm_init_kernel<64, false, false><<<gNod64, 256, 0, stream>>>(x, nullptr, w1_init, w1_root, dinv, gatherA, rootb, nullptr, b1, N);
    prop_mm_kernel<<<gNod16, 256, 0, stream>>>(gatherA, off4, csr_boff, dinv, rootb, w1, gatherB, N);
    prop_mean_kernel<<<gNod16, 256, 0, stream>>>(gatherB, off4, csr_boff, dinv, rootb, hbuf, N);

    // ---- layer 2 (act = identity; mean_k commutes through the tail) ----
    mm_init_kernel<32, true, true><<<gNod64, 256, 0, stream>>>(nullptr, hbuf, w2_init, w2_root, dinv, gatherA, rootb, rootm, b2, N);
    prop_mm_mean_kernel<<<gNod16, 256, 0, stream>>>(gatherA, off4, csr_boff, dinv, rootb, w2, grow2, N);
    prop_mean2_kernel<<<gNod16, 256, 0, stream>>>(grow2, off4, csr_boff, dinv, rootm, out, N);
}

// Round 17
// 327.543 us; speedup vs baseline: 1.0681x; 1.0681x over previous
//
#include <hip/hip_runtime.h>
#include <hip/hip_bf16.h>

// ARMA GNN (K=3 stacks, T=2 layers, F_in=64, DIM=32) on MI355X.
// Round 17: revert r16's non-temporal loads (FETCH rose 174->179MB, props
// 65->70us — nt evicted lines that adjacent groups still needed). Keep the
// merged scan23 and fill+dummy-zero fusion. Core = r14/r15 structure.

#define KSTACK 3
#define DIM    32
#define FDIM   96    // KSTACK*DIM
#define NB     256   // dst buckets (dst>>9; N<=131072)
#define TILE   4096  // edges per grouping block

typedef __hip_bfloat16 bf16;
typedef _Float16 f16;
typedef _Float16 halfx2 __attribute__((ext_vector_type(2)));

__device__ __forceinline__ float dot2h(unsigned int a, unsigned int b, float c) {
#if __has_builtin(__builtin_amdgcn_fdot2)
    return __builtin_amdgcn_fdot2(__builtin_bit_cast(halfx2, a),
                                  __builtin_bit_cast(halfx2, b), c, false);
#else
    halfx2 ha = __builtin_bit_cast(halfx2, a);
    halfx2 hb = __builtin_bit_cast(halfx2, b);
    return c + (float)ha.x * (float)hb.x + (float)ha.y * (float)hb.y;
#endif
}

__device__ __forceinline__ unsigned int pkh(float lo, float hi) {
    return __builtin_bit_cast(unsigned int, __builtin_amdgcn_cvt_pkrtz(lo, hi));
}

__device__ __forceinline__ halfx2 h2(unsigned int q) {
    return __builtin_bit_cast(halfx2, q);
}

// ---------------- graph build (no random global atomics) ----------------

__global__ void zero_int_kernel(int* __restrict__ p, int n) {
    int i = blockIdx.x * 256 + threadIdx.x;
    if (i < n) p[i] = 0;
}

// per-block LDS histogram of dst>>9 -> global bcnt (256 low-contention atomics/block)
__global__ __launch_bounds__(256) void bucket_hist_kernel(const int* __restrict__ dst,
                                                          int* __restrict__ bcnt, int E) {
    __shared__ int cnt[NB];
    for (int i = threadIdx.x; i < NB; i += 256) cnt[i] = 0;
    __syncthreads();
    const int e0 = blockIdx.x * TILE;
    const int count = min(TILE, E - e0);
    for (int u = threadIdx.x; u < count; u += 256)
        atomicAdd(&cnt[dst[e0 + u] >> 9], 1);
    __syncthreads();
    for (int i = threadIdx.x; i < NB; i += 256)
        if (cnt[i]) atomicAdd(&bcnt[i], cnt[i]);
}

__global__ __launch_bounds__(256) void bucket_scan_kernel(const int* __restrict__ bcnt,
                                                          int* __restrict__ gcur,
                                                          int* __restrict__ gbase) {
    __shared__ int s[NB];
    const int t = threadIdx.x;
    int v = bcnt[t];
    s[t] = v;
    __syncthreads();
    for (int off = 1; off < NB; off <<= 1) {
        int add = (t >= off) ? s[t - off] : 0;
        __syncthreads();
        s[t] += add;
        __syncthreads();
    }
    gcur[t]  = s[t] - v;   // mutable cursor for chunk reservation
    gbase[t] = s[t] - v;   // stable bucket base
}

// counting-sort pass: group edges by dst>>9; packed u32 output ((dst&511)<<23|src)
__global__ __launch_bounds__(256) void group_edges_kernel(
    const int* __restrict__ src, const int* __restrict__ dst,
    int* __restrict__ gcur, unsigned int* __restrict__ grouped, int E)
{
    __shared__ int cnt[NB], pref[NB], lbase[NB], lofs[NB], gres[NB];
    __shared__ int2 stage[TILE];
    const int tid = threadIdx.x;
    const int e0 = blockIdx.x * TILE;
    const int count = min(TILE, E - e0);
    cnt[tid] = 0;
    __syncthreads();
    #pragma unroll
    for (int u = 0; u < TILE / 256; ++u) {
        int idx = u * 256 + tid;
        if (idx < count) atomicAdd(&cnt[dst[e0 + idx] >> 9], 1);
    }
    __syncthreads();
    int v = cnt[tid];
    pref[tid] = v;
    __syncthreads();
    for (int off = 1; off < NB; off <<= 1) {
        int add = (tid >= off) ? pref[tid - off] : 0;
        __syncthreads();
        pref[tid] += add;
        __syncthreads();
    }
    int ex = pref[tid] - v;
    lbase[tid] = ex;
    lofs[tid]  = ex;
    gres[tid] = atomicAdd(&gcur[tid], v);   // reserve global chunk for this block
    __syncthreads();
    #pragma unroll
    for (int u = 0; u < TILE / 256; ++u) {
        int idx = u * 256 + tid;
        if (idx < count) {
            int e = e0 + idx;
            int d = dst[e];
            int lp = atomicAdd(&lofs[d >> 9], 1);
            stage[lp] = make_int2(src[e], d);
        }
    }
    __syncthreads();
    for (int i = tid; i < count; i += 256) {
        int2 pr = stage[i];
        int b = pr.y >> 9;
        grouped[gres[b] + (i - lbase[b])] =
            ((unsigned int)(pr.y & 511) << 23) | (unsigned int)pr.x;  // coalesced
    }
}

// fused per-bucket: degree histogram from grouped + dinv + deg4 scan -> off4
__global__ __launch_bounds__(512) void scan1_kernel(
    const unsigned int* __restrict__ grouped, const int* __restrict__ gbase,
    const int* __restrict__ bcnt, float* __restrict__ dinv,
    int* __restrict__ off4, int* __restrict__ bsums, int N)
{
    __shared__ int h[512];
    __shared__ int tmp[512];
    const int b  = blockIdx.x;
    const int t  = threadIdx.x;
    const int nb = b * 512;
    h[t] = 0;
    __syncthreads();
    const int e0 = gbase[b], cnt = bcnt[b];
    for (int u = t; u < cnt; u += 512)
        atomicAdd(&h[grouped[e0 + u] >> 23], 1);
    __syncthreads();
    const int i  = nb + t;
    const int dg = h[t];
    if (i < N) dinv[i] = (dg > 0) ? rsqrtf((float)dg) : 0.0f;
    int v = (i < N) ? ((dg + 3) & ~3) : 0;
    tmp[t] = v;
    __syncthreads();
    for (int off = 1; off < 512; off <<= 1) {
        int add = (t >= off) ? tmp[t - off] : 0;
        __syncthreads();
        tmp[t] += add;
        __syncthreads();
    }
    if (i <= N) off4[i] = tmp[t] - v;            // block-local exclusive
    if (t == 511) bsums[b] = tmp[511];           // block total
}

// merged scan2+scan3: each block scans all (<=256) block sums in LDS, applies
__global__ __launch_bounds__(256) void scan23_kernel(int* __restrict__ off4,
                                                     const int* __restrict__ bsums,
                                                     int nsb, int N) {
    __shared__ int s[256], ex[256];
    const int t = threadIdx.x;
    int v = (t < nsb) ? bsums[t] : 0;
    s[t] = v;
    __syncthreads();
    for (int off = 1; off < 256; off <<= 1) {
        int add = (t >= off) ? s[t - off] : 0;
        __syncthreads();
        s[t] += add;
        __syncthreads();
    }
    ex[t] = s[t] - v;   // exclusive prefix
    __syncthreads();
    int i = blockIdx.x * 256 + t;
    if (i <= N) off4[i] += ex[i >> 9];
}

// per-bucket CSR fill: LDS cursors seeded from off4; fills edges + pad slots.
// Block 0 additionally zeroes the dummy rows of the three gather tables.
__global__ __launch_bounds__(256) void fill_csr_bucket_kernel(
    const unsigned int* __restrict__ grouped, const int* __restrict__ gbase,
    const int* __restrict__ bcnt, const int* __restrict__ off4,
    int* __restrict__ csr, f16* __restrict__ ga, f16* __restrict__ gb,
    f16* __restrict__ gc, int N, int dummy)
{
    __shared__ int lofs[512];
    const int b  = blockIdx.x;
    const int nb = b * 512;
    for (int i = threadIdx.x; i < 512; i += 256)
        lofs[i] = (nb + i < N) ? off4[nb + i] : 0;
    __syncthreads();
    const int e0 = gbase[b], cnt = bcnt[b];
    for (int u = threadIdx.x; u < cnt; u += 256) {
        unsigned int pe = grouped[e0 + u];
        int pos = atomicAdd(&lofs[pe >> 23], 1);
        csr[pos] = (int)(pe & 0x7fffffu) << 6;   // src*64
    }
    __syncthreads();
    for (int i = threadIdx.x; i < 512; i += 256) {
        int n = nb + i;
        if (n < N) {
            int p = lofs[i];            // = off4[n] + deg[n]
            int e = off4[n + 1];
            for (; p < e; ++p) csr[p] = dummy;
        }
    }
    if (b == 0) {
        int t = threadIdx.x;
        if (t < FDIM) {
            ga[(long)N * FDIM + t] = (f16)0.f;
            gb[(long)N * FDIM + t] = (f16)0.f;
        }
        if (t < DIM) gc[(long)N * DIM + t] = (f16)0.f;
    }
}

// ---------------- init GEMM (packed-f16 dot2) ----------------
// 64 nodes/block; thread (g,o): nodes 8g..8g+7, output col o, all 3 stacks.
// x staged as packed f16 pairs [F2][64]; weights as packed-pair tables.
// outA (gather table) and rootb (bias folded) written f16.

template <int FIN, bool MEANROOT, bool XF16>
__global__ __launch_bounds__(256) void mm_init_kernel(
    const float* __restrict__ xf,   // [N, FIN] fp32 (if !XF16)
    const f16*   __restrict__ xh,   // [N, FIN] f16  (if XF16)
    const float* __restrict__ wA,   // [K, FIN, 32]
    const float* __restrict__ wB,   // [K, FIN, 32]
    const float* __restrict__ dinv, // [N]
    f16*   __restrict__ outA,       // [N+1, 96] f16 (row N maintained elsewhere)
    f16*   __restrict__ rootb,      // [N, 96] f16, = x@wB + bias
    float* __restrict__ rootm,      // [N, 32] = mean_k(x@wB + bias)   (if MEANROOT)
    const float* __restrict__ bias, // [96]
    int N)
{
    constexpr int F2 = FIN / 2;
    __shared__ unsigned int swA2[KSTACK * F2 * 32];
    __shared__ unsigned int swB2[KSTACK * F2 * 32];
    __shared__ unsigned int sx2[F2 * 64];
    const int tid = threadIdx.x;
    const int n0  = blockIdx.x * 64;

    for (int i = tid; i < KSTACK * F2 * 32; i += 256) {
        int k = i / (F2 * 32), r = i % (F2 * 32), f2 = r >> 5, o = r & 31;
        swA2[i] = pkh(wA[(k * FIN + 2 * f2) * 32 + o], wA[(k * FIN + 2 * f2 + 1) * 32 + o]);
        swB2[i] = pkh(wB[(k * FIN + 2 * f2) * 32 + o], wB[(k * FIN + 2 * f2 + 1) * 32 + o]);
    }
    for (int i = tid; i < 64 * F2; i += 256) {
        int jj = i / F2, f2 = i % F2;
        int n = n0 + jj; if (n >= N) n = N - 1;
        unsigned int v;
        if (XF16) v = *reinterpret_cast<const unsigned int*>(xh + (long)n * FIN + 2 * f2);
        else      v = pkh(xf[(long)n * FIN + 2 * f2], xf[(long)n * FIN + 2 * f2 + 1]);
        sx2[f2 * 64 + jj] = v;
    }
    __syncthreads();

    const int o = tid & 31;
    const int g = tid >> 5;
    float bz[KSTACK];
    #pragma unroll
    for (int k = 0; k < KSTACK; ++k) bz[k] = bias[k * 32 + o];
    float accA[8][KSTACK];
    float accB[8][KSTACK];
    #pragma unroll
    for (int jj = 0; jj < 8; ++jj)
        #pragma unroll
        for (int k = 0; k < KSTACK; ++k) { accA[jj][k] = 0.f; accB[jj][k] = 0.f; }

    #pragma unroll 2
    for (int f2 = 0; f2 < F2; ++f2) {
        uint4 xlo = *reinterpret_cast<const uint4*>(&sx2[f2 * 64 + 8 * g]);
        uint4 xhi = *reinterpret_cast<const uint4*>(&sx2[f2 * 64 + 8 * g + 4]);
        unsigned int xp[8] = {xlo.x, xlo.y, xlo.z, xlo.w, xhi.x, xhi.y, xhi.z, xhi.w};
        #pragma unroll
        for (int k = 0; k < KSTACK; ++k) {
            unsigned int wa2 = swA2[(k * F2 + f2) * 32 + o];
            unsigned int wb2 = swB2[(k * F2 + f2) * 32 + o];
            #pragma unroll
            for (int jj = 0; jj < 8; ++jj) {
                accA[jj][k] = dot2h(xp[jj], wa2, accA[jj][k]);
                accB[jj][k] = dot2h(xp[jj], wb2, accB[jj][k]);
            }
        }
    }

    #pragma unroll
    for (int jj = 0; jj < 8; ++jj) {
        long n = n0 + 8 * g + jj;
        if (n < N) {
            const float di = dinv[n];
            float rsum = 0.f;
            #pragma unroll
            for (int k = 0; k < KSTACK; ++k) {
                float rb = accB[jj][k] + bz[k];
                outA[n * FDIM + k * 32 + o]  = (f16)(accA[jj][k] * di);
                rootb[n * FDIM + k * 32 + o] = (f16)rb;
                rsum += rb;
            }
            if (MEANROOT)
                rootm[n * 32 + o] = rsum * (1.0f / 3.0f);
        }
    }
}

// ---------------- gather helpers ----------------

// dual-dst gather over 192B f16 rows, unroll 8 (16 row-loads + 4 offset-loads
// in flight per 32-lane group). csr stores src*64; 192B-row offset = 3*o.
// Packed f16 adds, two interleaved chains. Pad slots predicated to dummy row.
#define GATHER_LOOP8()                                                         \
    const int m = max(nA, nB);                                                 \
    halfx2 aA01a = {0, 0}, aA23a = {0, 0}, aA01b = {0, 0}, aA23b = {0, 0};     \
    halfx2 aB01a = {0, 0}, aB23a = {0, 0}, aB01b = {0, 0}, aB23b = {0, 0};     \
    for (int b = 0; b < m; b += 8) {                                           \
        int4 tA0 = *reinterpret_cast<const int4*>(csr + iA + b);               \
        int4 tA1 = *reinterpret_cast<const int4*>(csr + iA + b + 4);           \
        int4 tB0 = *reinterpret_cast<const int4*>(csr + iB + b);               \
        int4 tB1 = *reinterpret_cast<const int4*>(csr + iB + b + 4);           \
        const int rA = nA - b, rB = nB - b;                                    \
        int oA0 = rA > 0 ? tA0.x : dummy;                                      \
        int oA1 = rA > 1 ? tA0.y : dummy;                                      \
        int oA2 = rA > 2 ? tA0.z : dummy;                                      \
        int oA3 = rA > 3 ? tA0.w : dummy;                                      \
        int oA4 = rA > 4 ? tA1.x : dummy;                                      \
        int oA5 = rA > 5 ? tA1.y : dummy;                                      \
        int oA6 = rA > 6 ? tA1.z : dummy;                                      \
        int oA7 = rA > 7 ? tA1.w : dummy;                                      \
        int oB0 = rB > 0 ? tB0.x : dummy;                                      \
        int oB1 = rB > 1 ? tB0.y : dummy;                                      \
        int oB2 = rB > 2 ? tB0.z : dummy;                                      \
        int oB3 = rB > 3 ? tB0.w : dummy;                                      \
        int oB4 = rB > 4 ? tB1.x : dummy;                                      \
        int oB5 = rB > 5 ? tB1.y : dummy;                                      \
        int oB6 = rB > 6 ? tB1.z : dummy;                                      \
        int oB7 = rB > 7 ? tB1.w : dummy;                                      \
        if (ld) {                                                              \
            uint2 qA0 = *reinterpret_cast<const uint2*>(base + 3 * oA0 + lb);  \
            uint2 qA1 = *reinterpret_cast<const uint2*>(base + 3 * oA1 + lb);  \
            uint2 qA2 = *reinterpret_cast<const uint2*>(base + 3 * oA2 + lb);  \
            uint2 qA3 = *reinterpret_cast<const uint2*>(base + 3 * oA3 + lb);  \
            uint2 qA4 = *reinterpret_cast<const uint2*>(base + 3 * oA4 + lb);  \
            uint2 qA5 = *reinterpret_cast<const uint2*>(base + 3 * oA5 + lb);  \
            uint2 qA6 = *reinterpret_cast<const uint2*>(base + 3 * oA6 + lb);  \
            uint2 qA7 = *reinterpret_cast<const uint2*>(base + 3 * oA7 + lb);  \
            uint2 qB0 = *reinterpret_cast<const uint2*>(base + 3 * oB0 + lb);  \
            uint2 qB1 = *reinterpret_cast<const uint2*>(base + 3 * oB1 + lb);  \
            uint2 qB2 = *reinterpret_cast<const uint2*>(base + 3 * oB2 + lb);  \
            uint2 qB3 = *reinterpret_cast<const uint2*>(base + 3 * oB3 + lb);  \
            uint2 qB4 = *reinterpret_cast<const uint2*>(base + 3 * oB4 + lb);  \
            uint2 qB5 = *reinterpret_cast<const uint2*>(base + 3 * oB5 + lb);  \
            uint2 qB6 = *reinterpret_cast<const uint2*>(base + 3 * oB6 + lb);  \
            uint2 qB7 = *reinterpret_cast<const uint2*>(base + 3 * oB7 + lb);  \
            aA01a += h2(qA0.x); aA23a += h2(qA0.y);                            \
            aA01b += h2(qA1.x); aA23b += h2(qA1.y);                            \
            aA01a += h2(qA2.x); aA23a += h2(qA2.y);                            \
            aA01b += h2(qA3.x); aA23b += h2(qA3.y);                            \
            aA01a += h2(qA4.x); aA23a += h2(qA4.y);                            \
            aA01b += h2(qA5.x); aA23b += h2(qA5.y);                            \
            aA01a += h2(qA6.x); aA23a += h2(qA6.y);                            \
            aA01b += h2(qA7.x); aA23b += h2(qA7.y);                            \
            aB01a += h2(qB0.x); aB23a += h2(qB0.y);                            \
            aB01b += h2(qB1.x); aB23b += h2(qB1.y);                            \
            aB01a += h2(qB2.x); aB23a += h2(qB2.y);                            \
            aB01b += h2(qB3.x); aB23b += h2(qB3.y);                            \
            aB01a += h2(qB4.x); aB23a += h2(qB4.y);                            \
            aB01b += h2(qB5.x); aB23b += h2(qB5.y);                            \
            aB01a += h2(qB6.x); aB23a += h2(qB6.y);                            \
            aB01b += h2(qB7.x); aB23b += h2(qB7.y);                            \
        }                                                                      \
    }                                                                          \
    const float aA0 = (float)aA01a.x + (float)aA01b.x;                         \
    const float aA1 = (float)aA01a.y + (float)aA01b.y;                         \
    const float aA2 = (float)aA23a.x + (float)aA23b.x;                         \
    const float aA3 = (float)aA23a.y + (float)aA23b.y;                         \
    const float aB0 = (float)aB01a.x + (float)aB01b.x;                         \
    const float aB1 = (float)aB01a.y + (float)aB01b.y;                         \
    const float aB2 = (float)aB23a.x + (float)aB23b.x;                         \
    const float aB3 = (float)aB23a.y + (float)aB23b.y;

// setup shared by all dual-dst gather kernels (f16 root, bias folded)
#define DST_SETUP()                                                            \
    const int dA = blockIdx.x * 16 + j;                                        \
    const int dB = dA + 8;                                                     \
    const bool vA = dA < N, vB = dB < N;                                       \
    const int dummy = N * 64;                                                  \
    const bool ld  = lane < 24;                                                \
    const int  lb  = lane * 8;                                                 \
    const char* base = (const char*)in;                                        \
    halfx2 rA01 = {0, 0}, rA23 = {0, 0}, rB01 = {0, 0}, rB23 = {0, 0};         \
    int iA = 0, nA = 0, iB = 0, nB = 0;                                        \
    float diA = 0.f, diB = 0.f;                                                \
    if (vA) {                                                                  \
        iA = off4[dA]; nA = off4[dA + 1] - iA; diA = dinv[dA];                 \
        if (ld) {                                                              \
            uint2 rr = *reinterpret_cast<const uint2*>(                        \
                (const char*)root + (long)dA * 192 + lb);                      \
            rA01 = h2(rr.x); rA23 = h2(rr.y);                                  \
        }                                                                      \
    }                                                                          \
    if (vB) {                                                                  \
        iB = off4[dB]; nB = off4[dB + 1] - iB; diB = dinv[dB];                 \
        if (ld) {                                                              \
            uint2 rr = *reinterpret_cast<const uint2*>(                        \
                (const char*)root + (long)dB * 192 + lb);                      \
            rB01 = h2(rr.x); rB23 = h2(rr.y);                                  \
        }                                                                      \
    }

// packed-f16 96-wide GEMV: r_k = sum_f v[k*32+f] * w[k][f][lane]
__device__ __forceinline__ void gemv96(const unsigned int* __restrict__ sv,
                                       const unsigned int* __restrict__ sw2,
                                       int lane, float& r0, float& r1, float& r2) {
    float o[KSTACK];
    #pragma unroll
    for (int k = 0; k < KSTACK; ++k) {
        const unsigned int* sp = sv + k * 16;
        uint4 s0 = *reinterpret_cast<const uint4*>(sp);
        uint4 s1 = *reinterpret_cast<const uint4*>(sp + 4);
        uint4 s2 = *reinterpret_cast<const uint4*>(sp + 8);
        uint4 s3 = *reinterpret_cast<const uint4*>(sp + 12);
        const unsigned int* wp = sw2 + k * 512 + lane;
        float a = 0.f;
        a = dot2h(s0.x, wp[0],   a); a = dot2h(s0.y, wp[32],  a);
        a = dot2h(s0.z, wp[64],  a); a = dot2h(s0.w, wp[96],  a);
        a = dot2h(s1.x, wp[128], a); a = dot2h(s1.y, wp[160], a);
        a = dot2h(s1.z, wp[192], a); a = dot2h(s1.w, wp[224], a);
        a = dot2h(s2.x, wp[256], a); a = dot2h(s2.y, wp[288], a);
        a = dot2h(s2.z, wp[320], a); a = dot2h(s2.w, wp[352], a);
        a = dot2h(s3.x, wp[384], a); a = dot2h(s3.y, wp[416], a);
        a = dot2h(s3.z, wp[448], a); a = dot2h(s3.w, wp[480], a);
        o[k] = a;
    }
    r0 = o[0]; r1 = o[1]; r2 = o[2];
}

// ---------------- prop #1 (layer 1): gather + relu + fused 32x32 GEMV ------
__global__ __launch_bounds__(256) void prop_mm_kernel(
    const f16*   __restrict__ in,       // [N+1, 96] pre-scaled by dinv[src]
    const int*   __restrict__ off4,     // [N+1]
    const int*   __restrict__ csr,      // src*64, 4-aligned segments
    const float* __restrict__ dinv,
    const f16*   __restrict__ root,     // [N, 96] f16, bias folded
    const float* __restrict__ w,        // [K,32,32]
    f16* __restrict__ out, int N)       // [N+1, 96]; row N maintained elsewhere
{
    __shared__ unsigned int sw2[KSTACK * 512];   // lane-major packed-f16 weight pairs
    __shared__ unsigned int sv2[16][48];         // packed-f16 activated vectors
    const int tid = threadIdx.x;
    for (int i = tid; i < KSTACK * 512; i += 256) {
        int k = i >> 9, r = i & 511, t = r >> 5, o = r & 31;
        sw2[i] = pkh(w[(k * 32 + 2 * t) * 32 + o], w[(k * 32 + 2 * t + 1) * 32 + o]);
    }
    __syncthreads();
    const int lane = tid & 31;
    const int j    = tid >> 5;
    DST_SETUP();

    GATHER_LOOP8();

    if (ld) {
        if (vA) {
            float v0 = fmaxf(aA0 * diA + (float)rA01.x, 0.f);
            float v1 = fmaxf(aA1 * diA + (float)rA01.y, 0.f);
            float v2 = fmaxf(aA2 * diA + (float)rA23.x, 0.f);
            float v3 = fmaxf(aA3 * diA + (float)rA23.y, 0.f);
            sv2[j][2 * lane]     = pkh(v0, v1);
            sv2[j][2 * lane + 1] = pkh(v2, v3);
        }
        if (vB) {
            float v0 = fmaxf(aB0 * diB + (float)rB01.x, 0.f);
            float v1 = fmaxf(aB1 * diB + (float)rB01.y, 0.f);
            float v2 = fmaxf(aB2 * diB + (float)rB23.x, 0.f);
            float v3 = fmaxf(aB3 * diB + (float)rB23.y, 0.f);
            sv2[j + 8][2 * lane]     = pkh(v0, v1);
            sv2[j + 8][2 * lane + 1] = pkh(v2, v3);
        }
    }
    // same-wave LDS write->read: no barrier needed
    if (vA) {
        float o0, o1, o2;
        gemv96(&sv2[j][0], sw2, lane, o0, o1, o2);
        out[(long)dA * FDIM + lane]      = (f16)(o0 * diA);
        out[(long)dA * FDIM + 32 + lane] = (f16)(o1 * diA);
        out[(long)dA * FDIM + 64 + lane] = (f16)(o2 * diA);
    }
    if (vB) {
        float o0, o1, o2;
        gemv96(&sv2[j + 8][0], sw2, lane, o0, o1, o2);
        out[(long)dB * FDIM + lane]      = (f16)(o0 * diB);
        out[(long)dB * FDIM + 32 + lane] = (f16)(o1 * diB);
        out[(long)dB * FDIM + 64 + lane] = (f16)(o2 * diB);
    }
}

// -------- prop #2 (layer 1): gather + relu + mean over stacks + relu -------
__global__ __launch_bounds__(256) void prop_mean_kernel(
    const f16*   __restrict__ in,       // [N+1, 96] pre-scaled by dinv[src]
    const int*   __restrict__ off4,
    const int*   __restrict__ csr,
    const float* __restrict__ dinv,
    const f16*   __restrict__ root,     // [N, 96] f16, bias folded
    f16* __restrict__ out,              // [N, 32] f16
    int N)
{
    __shared__ float sv[16][FDIM];
    const int tid = threadIdx.x;
    const int lane = tid & 31;
    const int j    = tid >> 5;
    DST_SETUP();

    GATHER_LOOP8();

    if (ld) {
        if (vA) {
            sv[j][4*lane]   = fmaxf(aA0 * diA + (float)rA01.x, 0.f);
            sv[j][4*lane+1] = fmaxf(aA1 * diA + (float)rA01.y, 0.f);
            sv[j][4*lane+2] = fmaxf(aA2 * diA + (float)rA23.x, 0.f);
            sv[j][4*lane+3] = fmaxf(aA3 * diA + (float)rA23.y, 0.f);
        }
        if (vB) {
            sv[j+8][4*lane]   = fmaxf(aB0 * diB + (float)rB01.x, 0.f);
            sv[j+8][4*lane+1] = fmaxf(aB1 * diB + (float)rB01.y, 0.f);
            sv[j+8][4*lane+2] = fmaxf(aB2 * diB + (float)rB23.x, 0.f);
            sv[j+8][4*lane+3] = fmaxf(aB3 * diB + (float)rB23.y, 0.f);
        }
    }
    if (vA) {
        float mv = fmaxf((sv[j][lane] + sv[j][32 + lane] + sv[j][64 + lane]) * (1.0f / 3.0f), 0.f);
        out[(long)dA * 32 + lane] = (f16)mv;
    }
    if (vB) {
        float mv = fmaxf((sv[j+8][lane] + sv[j+8][32 + lane] + sv[j+8][64 + lane]) * (1.0f / 3.0f), 0.f);
        out[(long)dB * 32 + lane] = (f16)mv;
    }
}

// ---- prop #3 (layer 2): gather + identity + GEMV, write k-MEAN (32-wide) ---
__global__ __launch_bounds__(256) void prop_mm_mean_kernel(
    const f16*   __restrict__ in,       // [N+1, 96] pre-scaled by dinv[src]
    const int*   __restrict__ off4,
    const int*   __restrict__ csr,
    const float* __restrict__ dinv,
    const f16*   __restrict__ root,     // [N, 96] f16, bias folded
    const float* __restrict__ w,        // [K,32,32]
    f16* __restrict__ out, int N)       // [N+1, 32]; row N maintained elsewhere
{
    __shared__ unsigned int sw2[KSTACK * 512];
    __shared__ unsigned int sv2[16][48];
    const int tid = threadIdx.x;
    for (int i = tid; i < KSTACK * 512; i += 256) {
        int k = i >> 9, r = i & 511, t = r >> 5, o = r & 31;
        sw2[i] = pkh(w[(k * 32 + 2 * t) * 32 + o], w[(k * 32 + 2 * t + 1) * 32 + o]);
    }
    __syncthreads();
    const int lane = tid & 31;
    const int j    = tid >> 5;
    DST_SETUP();

    GATHER_LOOP8();

    if (ld) {
        if (vA) {
            sv2[j][2 * lane]     = pkh(aA0 * diA + (float)rA01.x, aA1 * diA + (float)rA01.y);
            sv2[j][2 * lane + 1] = pkh(aA2 * diA + (float)rA23.x, aA3 * diA + (float)rA23.y);
        }
        if (vB) {
            sv2[j + 8][2 * lane]     = pkh(aB0 * diB + (float)rB01.x, aB1 * diB + (float)rB01.y);
            sv2[j + 8][2 * lane + 1] = pkh(aB2 * diB + (float)rB23.x, aB3 * diB + (float)rB23.y);
        }
    }
    // same-wave LDS write->read: no barrier needed
    if (vA) {
        float o0, o1, o2;
        gemv96(&sv2[j][0], sw2, lane, o0, o1, o2);
        out[(long)dA * 32 + lane] = (f16)((o0 + o1 + o2) * (diA * (1.0f / 3.0f)));
    }
    if (vB) {
        float o0, o1, o2;
        gemv96(&sv2[j + 8][0], sw2, lane, o0, o1, o2);
        out[(long)dB * 32 + lane] = (f16)((o0 + o1 + o2) * (diB * (1.0f / 3.0f)));
    }
}

// ---- prop #4 (layer 2, final): 64B-row gather + rootm add (fp32 out) ------
__global__ __launch_bounds__(256) void prop_mean2_kernel(
    const f16*   __restrict__ in,       // [N+1, 32] k-mean rows, dinv-prescaled
    const int*   __restrict__ off4,
    const int*   __restrict__ csr,      // src*64
    const float* __restrict__ dinv,
    const float* __restrict__ rootm,    // [N, 32] mean_k(root) incl. bias
    float* __restrict__ out,            // [N, 32]
    int N)
{
    const int lane = threadIdx.x & 15;
    const int g    = threadIdx.x >> 4;      // 16 groups/block
    const int d    = blockIdx.x * 16 + g;
    if (d >= N) return;
    const int dummy = N * 64;
    const int lb = lane * 4;                 // 4B (2 features) per lane
    const char* base = (const char*)in;
    const int i0 = off4[d];
    const int n  = off4[d + 1] - i0;
    halfx2 aa = {0, 0}, ab = {0, 0};
    for (int b = 0; b < n; b += 8) {
        int4 t0 = *reinterpret_cast<const int4*>(csr + i0 + b);
        int4 t1 = *reinterpret_cast<const int4*>(csr + i0 + b + 4);
        const int r = n - b;
        int o0 = r > 0 ? t0.x : dummy;
        int o1 = r > 1 ? t0.y : dummy;
        int o2 = r > 2 ? t0.z : dummy;
        int o3 = r > 3 ? t0.w : dummy;
        int o4 = r > 4 ? t1.x : dummy;
        int o5 = r > 5 ? t1.y : dummy;
        int o6 = r > 6 ? t1.z : dummy;
        int o7 = r > 7 ? t1.w : dummy;
        unsigned int q0 = *reinterpret_cast<const unsigned int*>(base + o0 + lb);
        unsigned int q1 = *reinterpret_cast<const unsigned int*>(base + o1 + lb);
        unsigned int q2 = *reinterpret_cast<const unsigned int*>(base + o2 + lb);
        unsigned int q3 = *reinterpret_cast<const unsigned int*>(base + o3 + lb);
        unsigned int q4 = *reinterpret_cast<const unsigned int*>(base + o4 + lb);
        unsigned int q5 = *reinterpret_cast<const unsigned int*>(base + o5 + lb);
        unsigned int q6 = *reinterpret_cast<const unsigned int*>(base + o6 + lb);
        unsigned int q7 = *reinterpret_cast<const unsigned int*>(base + o7 + lb);
        aa += h2(q0); ab += h2(q1); aa += h2(q2); ab += h2(q3);
        aa += h2(q4); ab += h2(q5); aa += h2(q6); ab += h2(q7);
    }
    const float di = dinv[d];
    float a0 = (float)aa.x + (float)ab.x;
    float a1 = (float)aa.y + (float)ab.y;
    float2 rm = *reinterpret_cast<const float2*>(rootm + (long)d * 32 + 2 * lane);
    float2 res = make_float2(a0 * di + rm.x, a1 * di + rm.y);
    *reinterpret_cast<float2*>(out + (long)d * 32 + 2 * lane) = res;
}

// ---------------- launch ----------------

extern "C" void kernel_launch(void* const* d_in, const int* in_sizes, int n_in,
                              void* d_out, int out_size, void* d_ws, size_t ws_size,
                              hipStream_t stream) {
    const float* x       = (const float*)d_in[0];
    const int*   edge    = (const int*)  d_in[1];
    const float* w1_init = (const float*)d_in[2];
    const float* w1      = (const float*)d_in[3];
    const float* w1_root = (const float*)d_in[4];
    const float* b1      = (const float*)d_in[5];
    const float* w2_init = (const float*)d_in[6];
    const float* w2      = (const float*)d_in[7];
    const float* w2_root = (const float*)d_in[8];
    const float* b2      = (const float*)d_in[9];
    float* out = (float*)d_out;

    const int N = in_sizes[0] / 64;
    const int E = in_sizes[1] / 2;
    const int* src = edge;
    const int* dst = edge + E;
    const int E4max = E + 3 * N;   // upper bound on padded CSR length

    // workspace carve (256B aligned)
    char* p = (char*)d_ws;
    auto alloc = [&](size_t bytes) { void* r = (void*)p; p += (bytes + 255) & ~(size_t)255; return r; };
    float* dinv     = (float*)alloc((size_t)N * 4);
    int*   off4     = (int*)  alloc((size_t)(N + 1) * 4);
    const int nScanBlocks = (N + 1 + 511) / 512;   // == per-bucket scan1 grid
    int*   bsums    = (int*)  alloc((size_t)nScanBlocks * 4);
    int*   bcnt     = (int*)  alloc((size_t)NB * 4);
    int*   gcur     = (int*)  alloc((size_t)NB * 4);
    int*   gbase    = (int*)  alloc((size_t)NB * 4);
    int*   csr_boff = (int*)  alloc((size_t)(E4max + 1024) * 4);
    f16*   gatherA  = (f16*)  alloc((size_t)(N + 1) * FDIM * 2);
    f16*   gatherB  = (f16*)  alloc((size_t)(N + 1) * FDIM * 2);
    f16*   grow2    = (f16*)  alloc((size_t)(N + 1) * DIM * 2);
    f16*   rootb    = (f16*)  alloc((size_t)N * FDIM * 2);
    float* rootm    = (float*)alloc((size_t)N * DIM * 4);
    f16*   hbuf     = (f16*)  alloc((size_t)N * DIM * 2);
    unsigned int* grouped = (unsigned int*)alloc((size_t)E * 4);
    (void)ws_size; (void)n_in; (void)out_size;

    const int gN1    = (N + 1 + 255) / 256;
    const int gT     = (E + TILE - 1) / TILE;
    const int gNod64 = (N + 63) / 64;     // 64 rows per block (mm_init)
    const int gNod16 = (N + 15) / 16;     // 16 dst per block (props)

    // ---- graph structure (rebuilt every call; deterministic topology) ----
    zero_int_kernel<<<1, 256, 0, stream>>>(bcnt, NB);
    bucket_hist_kernel<<<gT, 256, 0, stream>>>(dst, bcnt, E);
    bucket_scan_kernel<<<1, NB, 0, stream>>>(bcnt, gcur, gbase);
    group_edges_kernel<<<gT, 256, 0, stream>>>(src, dst, gcur, grouped, E);
    scan1_kernel<<<nScanBlocks, 512, 0, stream>>>(grouped, gbase, bcnt, dinv, off4, bsums, N);
    scan23_kernel<<<gN1, 256, 0, stream>>>(off4, bsums, nScanBlocks, N);
    fill_csr_bucket_kernel<<<nScanBlocks, 256, 0, stream>>>(grouped, gbase, bcnt, off4,
                                                            csr_boff, gatherA, gatherB, grow2,
                                                            N, N * 64);

    // ---- layer 1 (act = relu) ----
    mm_init_kernel<64, false, false><<<gNod64, 256, 0, stream>>>(x, nullptr, w1_init, w1_root, dinv, gatherA, rootb, nullptr, b1, N);
    prop_mm_kernel<<<gNod16, 256, 0, stream>>>(gatherA, off4, csr_boff, dinv, rootb, w1, gatherB, N);
    prop_mean_kernel<<<gNod16, 256, 0, stream>>>(gatherB, off4, csr_boff, dinv, rootb, hbuf, N);

    // ---- layer 2 (act = identity; mean_k commutes through the tail) ----
    mm_init_kernel<32, true, true><<<gNod64, 256, 0, stream>>>(nullptr, hbuf, w2_init, w2_root, dinv, gatherA, rootb, rootm, b2, N);
    prop_mm_mean_kernel<<<gNod16, 256, 0, stream>>>(gatherA, off4, csr_boff, dinv, rootb, w2, grow2, N);
    prop_mean2_kernel<<<gNod16, 256, 0, stream>>>(grow2, off4, csr_boff, dinv, rootm, out, N);
}